// Round 5
// baseline (194.154 us; speedup 1.0000x reference)
//
#include <hip/hip_runtime.h>
#include <cmath>

#define TWO_PI_128 0.04908738521234052f  // 2*pi/128

typedef __attribute__((ext_vector_type(8))) short bf16x8;
typedef __attribute__((ext_vector_type(4))) float f32x4;

__device__ inline unsigned short f2bf(float v) {
  unsigned u = __float_as_uint(v);
  unsigned r = (u + 0x7FFFu + ((u >> 16) & 1u)) >> 16;
  return (unsigned short)r;
}
__device__ inline float bf2f(unsigned short s) {
  return __uint_as_float(((unsigned)s) << 16);
}
__device__ inline unsigned pack2(float a, float b) {
  return (unsigned)f2bf(a) | ((unsigned)f2bf(b) << 16);
}
__device__ inline float gelu_fast(float v) {
  // tanh-form GELU; max |diff| vs exact erf-GELU ~1e-3 (within budget)
  float z = 0.7978845608f * fmaf(0.044715f * v, v * v, v);
  float e = __expf(2.f * z);
  float th = 1.f - 2.f / (e + 1.f);
  return 0.5f * v * (1.f + th);
}

// ---------------------------------------------------------------------------
// setup: block 0 builds twiddle-fragment tables; blocks 1..16 compute proj.
//   ftab1[lane][8]  : fwd step-1 A-frags (a_re[0..3], a_im[0..3])
//   ftab2[t][4]     : fwd step-2 A-frags (kl2=0: ar,ai; kl2=1: ar,ai)
//   stab [t][2]     : final spectral B-frags (nt=0,1)
// ---------------------------------------------------------------------------
__global__ __launch_bounds__(256) void setup_kernel(
    const float* __restrict__ t_emb, const float* __restrict__ temb_w,
    const float* __restrict__ temb_b, float* __restrict__ proj,
    uint4* __restrict__ ftab1, uint4* __restrict__ ftab2,
    uint4* __restrict__ stab) {
  const int t = threadIdx.x;
  if (blockIdx.x == 0) {
    const int lane = t & 63, l15 = lane & 15, quad = lane >> 4;
    const int wv = t >> 6;
    union U8 {
      uint4 q;
      unsigned short u[8];
    };
    float dC, dS;
    sincosf(TWO_PI_128 * (float)l15, &dS, &dC);
    if (t < 64) {  // fwd step-1 frags (lane-indexed)
#pragma unroll
      for (int ks = 0; ks < 4; ++ks) {
        const int w0 = ks * 32 + quad * 8;
        float c, s;
        sincosf(TWO_PI_128 * (float)((l15 * w0) & 127), &s, &c);
        U8 re, im;
#pragma unroll
        for (int j = 0; j < 8; ++j) {
          re.u[j] = f2bf(c);
          im.u[j] = f2bf(-s);
          float nc = c * dC - s * dS;
          s = s * dC + c * dS;
          c = nc;
        }
        ftab1[lane * 8 + ks] = re.q;
        ftab1[lane * 8 + 4 + ks] = im.q;
      }
    }
    {  // fwd step-2 frags (t-indexed)
#pragma unroll
      for (int kl2 = 0; kl2 < 2; ++kl2) {
        const int ks2 = wv * 2 + kl2;
        const int hb = (ks2 & 3) * 32 + quad * 8;
        const int imh = ks2 >> 2;
        float c, s;
        sincosf(TWO_PI_128 * (float)((l15 * hb) & 127), &s, &c);
        U8 ar, ai;
#pragma unroll
        for (int j = 0; j < 8; ++j) {
          if (!imh) {
            ar.u[j] = f2bf(c);
            ai.u[j] = f2bf(-s);
          } else {
            ar.u[j] = f2bf(s);
            ai.u[j] = f2bf(c);
          }
          float nc = c * dC - s * dS;
          s = s * dC + c * dS;
          c = nc;
        }
        ftab2[t * 4 + kl2 * 2] = ar.q;
        ftab2[t * 4 + kl2 * 2 + 1] = ai.q;
      }
    }
    {  // final spectral B-frags (t-indexed)
      const int n0w = wv * 32;
      const int lbase = (quad & 1) * 8;
      const bool iscos = (quad < 2);
#pragma unroll
      for (int nt = 0; nt < 2; ++nt) {
        const int wn = n0w + nt * 16 + l15;
        float st, ct, ss, cc;
        sincosf(TWO_PI_128 * (float)wn, &st, &ct);
        sincosf(TWO_PI_128 * (float)(wn * lbase), &ss, &cc);
        U8 bs;
#pragma unroll
        for (int j = 0; j < 8; ++j) {
          bs.u[j] = f2bf(iscos ? cc : -ss);
          float nc = cc * ct - ss * st;
          ss = ss * ct + cc * st;
          cc = nc;
        }
        stab[t * 2 + nt] = bs.q;
      }
    }
    return;
  }
  // ---- proj for b = blockIdx.x - 1 ----
  __shared__ float s_silu[512];
  __shared__ float s_part[64][4];
  const int b = blockIdx.x - 1;
  for (int j = t; j < 512; j += 256) {
    float v = t_emb[b * 512 + j];
    s_silu[j] = v / (1.f + __expf(-v));
  }
  __syncthreads();
  const int o = t >> 2, part = t & 3;
  const float* wrow = temb_w + o * 512 + part * 128;
  const float* srow = s_silu + part * 128;
  float acc = 0.f;
#pragma unroll 8
  for (int j = 0; j < 128; ++j) acc = fmaf(srow[j], wrow[j], acc);
  s_part[o][part] = acc;
  __syncthreads();
  if (part == 0) {
    proj[b * 64 + o] =
        s_part[o][0] + s_part[o][1] + s_part[o][2] + s_part[o][3] + temb_b[o];
  }
}

// ---------------------------------------------------------------------------
// Forward truncated DFT per (b,i) plane — MFMA, twiddles from tables.
// ---------------------------------------------------------------------------
__global__ __launch_bounds__(256) void fwd_dft_kernel(
    const float* __restrict__ x, const uint4* __restrict__ ftab1,
    const uint4* __restrict__ ftab2, float* __restrict__ xfr_t,
    float* __restrict__ xfi_t) {
  __shared__ unsigned short s_x1[32 * 136];
  __shared__ float s_red[8 * 256];
  const int t = threadIdx.x;
  const int plane = blockIdx.x;
  const int wv = t >> 6, lane = t & 63, l15 = lane & 15, quad = lane >> 4;

  union U8 {
    uint4 q;
    bf16x8 v;
    unsigned short u[8];
  };

  U8 a_re[4], a_im[4];
#pragma unroll
  for (int ks = 0; ks < 4; ++ks) {
    a_re[ks].q = ftab1[lane * 8 + ks];
    a_im[ks].q = ftab1[lane * 8 + 4 + ks];
  }

  const float* xp = x + (size_t)plane * 16384;
  f32x4 acc[2][2];
#pragma unroll
  for (int mt = 0; mt < 2; ++mt)
#pragma unroll
    for (int nt = 0; nt < 2; ++nt) acc[mt][nt] = (f32x4){0.f, 0.f, 0.f, 0.f};

#pragma unroll
  for (int ks = 0; ks < 4; ++ks) {
#pragma unroll
    for (int nt = 0; nt < 2; ++nt) {
      const float* src =
          xp + (size_t)((wv * 2 + nt) * 16 + l15) * 128 + ks * 32 + quad * 8;
      float4 v0 = *(const float4*)src;
      float4 v1 = *(const float4*)(src + 4);
      U8 bx;
      bx.u[0] = f2bf(v0.x);
      bx.u[1] = f2bf(v0.y);
      bx.u[2] = f2bf(v0.z);
      bx.u[3] = f2bf(v0.w);
      bx.u[4] = f2bf(v1.x);
      bx.u[5] = f2bf(v1.y);
      bx.u[6] = f2bf(v1.z);
      bx.u[7] = f2bf(v1.w);
      acc[0][nt] = __builtin_amdgcn_mfma_f32_16x16x32_bf16(a_re[ks].v, bx.v,
                                                           acc[0][nt], 0, 0, 0);
      acc[1][nt] = __builtin_amdgcn_mfma_f32_16x16x32_bf16(a_im[ks].v, bx.v,
                                                           acc[1][nt], 0, 0, 0);
    }
  }

#pragma unroll
  for (int mt = 0; mt < 2; ++mt)
#pragma unroll
    for (int nt = 0; nt < 2; ++nt)
#pragma unroll
      for (int r = 0; r < 4; ++r)
        s_x1[(mt * 16 + quad * 4 + r) * 136 + (wv * 2 + nt) * 16 + l15] =
            f2bf(acc[mt][nt][r]);
  __syncthreads();

  f32x4 accre = (f32x4){0.f, 0.f, 0.f, 0.f};
  f32x4 accim = (f32x4){0.f, 0.f, 0.f, 0.f};
#pragma unroll
  for (int kl2 = 0; kl2 < 2; ++kl2) {
    const int ks2 = wv * 2 + kl2;
    const int hb = (ks2 & 3) * 32 + quad * 8;
    const int imh = ks2 >> 2;
    U8 ar, ai;
    ar.q = ftab2[t * 4 + kl2 * 2];
    ai.q = ftab2[t * 4 + kl2 * 2 + 1];
    bf16x8 bfrag = *(const bf16x8*)(s_x1 + (imh * 16 + l15) * 136 + hb);
    accre =
        __builtin_amdgcn_mfma_f32_16x16x32_bf16(ar.v, bfrag, accre, 0, 0, 0);
    accim =
        __builtin_amdgcn_mfma_f32_16x16x32_bf16(ai.v, bfrag, accim, 0, 0, 0);
  }
  *(f32x4*)(s_red + (wv * 2) * 256 + lane * 4) = accre;
  *(f32x4*)(s_red + (wv * 2 + 1) * 256 + lane * 4) = accim;
  __syncthreads();

  const float re = s_red[t] + s_red[512 + t] + s_red[1024 + t] + s_red[1536 + t];
  const float im =
      s_red[256 + t] + s_red[768 + t] + s_red[1280 + t] + s_red[1792 + t];
  const int k = (t >> 6) * 4 + (t & 3), l = (t >> 2) & 15;
  xfr_t[(size_t)(k * 16 + l) * 1024 + plane] = re * 0.0078125f;
  xfi_t[(size_t)(k * 16 + l) * 1024 + plane] = im * 0.0078125f;
}

// ---------------------------------------------------------------------------
// Mode mix: 2 kl per block (grid 128), weights read from ORIGINAL layout
// (float2 along kl — L3-hot), xf coalesced. Output bf16-packed kl-pairs.
// ---------------------------------------------------------------------------
__global__ __launch_bounds__(256) void modemix_kernel(
    const float* __restrict__ xfr_t, const float* __restrict__ xfi_t,
    const float* __restrict__ wr, const float* __restrict__ wi,
    unsigned* __restrict__ ofr_bf, unsigned* __restrict__ ofi_bf) {
  __shared__ float s_x[4][1024];  // [2*comp+klsub][bi]  16 KB
  __shared__ float s_w[4][4096];  // [2*comp+klsub][io]  64 KB
  const int klp = blockIdx.x, kl0 = klp * 2;
  const int t = threadIdx.x;
  {  // xf: rows kl0, kl0+1 contiguous per comp
    const float4* sr = (const float4*)(xfr_t + (size_t)kl0 * 1024);
    const float4* si = (const float4*)(xfi_t + (size_t)kl0 * 1024);
    ((float4*)&s_x[0][0])[t] = sr[t];
    ((float4*)&s_x[0][0])[t + 256] = sr[t + 256];
    ((float4*)&s_x[2][0])[t] = si[t];
    ((float4*)&s_x[2][0])[t + 256] = si[t + 256];
  }
#pragma unroll 4
  for (int j = 0; j < 16; ++j) {
    int io = t + 256 * j;
    float2 vr = *(const float2*)(wr + (size_t)io * 256 + kl0);
    float2 vi = *(const float2*)(wi + (size_t)io * 256 + kl0);
    s_w[0][io] = vr.x;
    s_w[1][io] = vr.y;
    s_w[2][io] = vi.x;
    s_w[3][io] = vi.y;
  }
  __syncthreads();
  const int b0 = t >> 6, o = t & 63;
  float rr[2][4], ri[2][4];
#pragma unroll
  for (int ks = 0; ks < 2; ++ks) {
    float accr[4] = {0.f, 0.f, 0.f, 0.f};
    float acci[4] = {0.f, 0.f, 0.f, 0.f};
    const float* xr = s_x[ks];
    const float* xi = s_x[2 + ks];
    const float* wrp = s_w[ks];
    const float* wip = s_w[2 + ks];
    for (int i = 0; i < 64; ++i) {
      float wrv = wrp[i * 64 + o], wiv = wip[i * 64 + o];
#pragma unroll
      for (int j = 0; j < 4; ++j) {
        int b = b0 + 4 * j;
        float xrv = xr[b * 64 + i], xiv = xi[b * 64 + i];
        accr[j] = fmaf(xrv, wrv, accr[j]);
        accr[j] = fmaf(-xiv, wiv, accr[j]);
        acci[j] = fmaf(xrv, wiv, acci[j]);
        acci[j] = fmaf(xiv, wrv, acci[j]);
      }
    }
#pragma unroll
    for (int j = 0; j < 4; ++j) {
      rr[ks][j] = accr[j];
      ri[ks][j] = acci[j];
    }
  }
#pragma unroll
  for (int j = 0; j < 4; ++j) {
    int plane = (b0 + 4 * j) * 64 + o;
    ofr_bf[(size_t)plane * 128 + klp] = pack2(rr[0][j], rr[1][j]);
    ofi_bf[(size_t)plane * 128 + klp] = pack2(ri[0][j], ri[1][j]);
  }
}

// ---------------------------------------------------------------------------
// Inverse along h (bf16 input). Output: packed bf16 Y[b][h][o][kk].
// ---------------------------------------------------------------------------
__global__ __launch_bounds__(256) void invh_kernel(
    const unsigned* __restrict__ ofr_bf, const unsigned* __restrict__ ofi_bf,
    uint4* __restrict__ Ybf) {
  __shared__ float s_fr[16 * 260], s_fi[16 * 260];
  __shared__ float2 s_tw[128];
  const int t = threadIdx.x;
  const int bid = blockIdx.x;
  const int b = bid >> 5, og = (bid >> 3) & 3, hg = bid & 7;
  if (t < 128) {
    float sv, cv;
    sincosf(TWO_PI_128 * (float)t, &sv, &cv);
    s_tw[t] = make_float2(cv, sv);
  }
#pragma unroll 4
  for (int pp = 0; pp < 8; ++pp) {
    const int row = pp * 2 + (t >> 7);
    const int col = t & 127;
    unsigned ur = ofr_bf[(size_t)(b * 64 + og * 16 + row) * 128 + col];
    unsigned ui = ofi_bf[(size_t)(b * 64 + og * 16 + row) * 128 + col];
    s_fr[row * 260 + 2 * col] = bf2f((unsigned short)(ur & 0xFFFFu));
    s_fr[row * 260 + 2 * col + 1] = bf2f((unsigned short)(ur >> 16));
    s_fi[row * 260 + 2 * col] = bf2f((unsigned short)(ui & 0xFFFFu));
    s_fi[row * 260 + 2 * col + 1] = bf2f((unsigned short)(ui >> 16));
  }
  __syncthreads();
  const int ol = t & 15, hl = t >> 4;
  const int h = hg * 16 + hl;
  float yr[16], yi[16];
#pragma unroll
  for (int l = 0; l < 16; ++l) {
    yr[l] = 0.f;
    yi[l] = 0.f;
  }
  const float* FR = s_fr + ol * 260;
  const float* FI = s_fi + ol * 260;
  const float2 tw = s_tw[h];
  float ck = 1.f, sk = 0.f;
#pragma unroll 4
  for (int k = 0; k < 16; ++k) {
#pragma unroll
    for (int q = 0; q < 4; ++q) {
      float4 fr = *(const float4*)(FR + k * 16 + 4 * q);
      float4 fi = *(const float4*)(FI + k * 16 + 4 * q);
      int l = 4 * q;
      yr[l + 0] = fmaf(fr.x, ck, yr[l + 0]);
      yr[l + 0] = fmaf(-fi.x, sk, yr[l + 0]);
      yi[l + 0] = fmaf(fi.x, ck, yi[l + 0]);
      yi[l + 0] = fmaf(fr.x, sk, yi[l + 0]);
      yr[l + 1] = fmaf(fr.y, ck, yr[l + 1]);
      yr[l + 1] = fmaf(-fi.y, sk, yr[l + 1]);
      yi[l + 1] = fmaf(fi.y, ck, yi[l + 1]);
      yi[l + 1] = fmaf(fr.y, sk, yi[l + 1]);
      yr[l + 2] = fmaf(fr.z, ck, yr[l + 2]);
      yr[l + 2] = fmaf(-fi.z, sk, yr[l + 2]);
      yi[l + 2] = fmaf(fi.z, ck, yi[l + 2]);
      yi[l + 2] = fmaf(fr.z, sk, yi[l + 2]);
      yr[l + 3] = fmaf(fr.w, ck, yr[l + 3]);
      yr[l + 3] = fmaf(-fi.w, sk, yr[l + 3]);
      yi[l + 3] = fmaf(fi.w, ck, yi[l + 3]);
      yi[l + 3] = fmaf(fr.w, sk, yi[l + 3]);
    }
    float tt = sk * tw.y, uu = ck * tw.y;
    ck = fmaf(ck, tw.x, -tt);
    sk = fmaf(sk, tw.x, uu);
  }
  unsigned int u[16];
#pragma unroll
  for (int j = 0; j < 8; ++j) {
    float s0 = (2 * j == 0) ? 0.0078125f : 0.015625f;
    u[j] = (unsigned)f2bf(yr[2 * j] * s0) |
           ((unsigned)f2bf(yr[2 * j + 1] * 0.015625f) << 16);
    u[8 + j] = (unsigned)f2bf(yi[2 * j] * s0) |
               ((unsigned)f2bf(yi[2 * j + 1] * 0.015625f) << 16);
  }
  uint4* dst = Ybf + ((size_t)(b * 128 + h) * 64 + og * 16 + ol) * 4;
  dst[0] = make_uint4(u[0], u[1], u[2], u[3]);
  dst[1] = make_uint4(u[4], u[5], u[6], u[7]);
  dst[2] = make_uint4(u[8], u[9], u[10], u[11]);
  dst[3] = make_uint4(u[12], u[13], u[14], u[15]);
}

// ---------------------------------------------------------------------------
// Final fused MFMA kernel; spectral B-frags from table, tanh-GELU epilogue.
// ---------------------------------------------------------------------------
__global__ __launch_bounds__(256) void final_kernel(
    const float* __restrict__ x, const float* __restrict__ bw,
    const float* __restrict__ bb, const float* __restrict__ proj,
    const uint4* __restrict__ Ybf, const uint4* __restrict__ stab,
    float* __restrict__ out) {
#define AR 104
  __shared__ unsigned short s_A[64 * AR];
  __shared__ float s_bb[64];
  __shared__ float s_pb[64];
  const int h = blockIdx.x, b = blockIdx.y, t = threadIdx.x;

  if (t < 64)
    s_bb[t] = bb[t];
  else if (t < 128)
    s_pb[t - 64] = proj[b * 64 + (t - 64)];

  {
    const int o = t >> 2, q = t & 3;
    const float4* src = (const float4*)(bw + o * 64 + q * 16);
    unsigned int u[8];
#pragma unroll
    for (int m = 0; m < 4; ++m) {
      float4 v = src[m];
      u[2 * m] = (unsigned)f2bf(v.x) | ((unsigned)f2bf(v.y) << 16);
      u[2 * m + 1] = (unsigned)f2bf(v.z) | ((unsigned)f2bf(v.w) << 16);
    }
    uint4* dst = (uint4*)(s_A + o * AR + q * 16);
    dst[0] = make_uint4(u[0], u[1], u[2], u[3]);
    dst[1] = make_uint4(u[4], u[5], u[6], u[7]);
  }
  {
    const int o = t >> 2, q = t & 3;
    uint4 v = Ybf[((size_t)(b * 128 + h) * 64 + o) * 4 + q];
    *(uint4*)(s_A + o * AR + 64 + q * 8) = v;
  }
  __syncthreads();

  const int wv = t >> 6, lane = t & 63;
  const int l15 = lane & 15, quad = lane >> 4;
  const int n0w = wv * 32;

  f32x4 acc[4][2];
#pragma unroll
  for (int mt = 0; mt < 4; ++mt) {
    f32x4 bv = *(const f32x4*)(s_bb + mt * 16 + quad * 4);
    acc[mt][0] = bv;
    acc[mt][1] = bv;
  }

  const float* xrow = x + (size_t)b * 1048576 + (size_t)h * 128 + n0w + l15;
#pragma unroll
  for (int ks = 0; ks < 64; ks += 32) {
    union {
      bf16x8 v;
      unsigned short u[8];
    } bx[2];
#pragma unroll
    for (int nt = 0; nt < 2; ++nt) {
      float xv[8];
#pragma unroll
      for (int j = 0; j < 8; ++j)
        xv[j] = xrow[(size_t)(ks + quad * 8 + j) * 16384 + nt * 16];
#pragma unroll
      for (int j = 0; j < 8; ++j) bx[nt].u[j] = f2bf(xv[j]);
    }
#pragma unroll
    for (int mt = 0; mt < 4; ++mt) {
      bf16x8 a = *(const bf16x8*)(s_A + (mt * 16 + l15) * AR + ks + quad * 8);
      acc[mt][0] = __builtin_amdgcn_mfma_f32_16x16x32_bf16(a, bx[0].v,
                                                           acc[mt][0], 0, 0, 0);
      acc[mt][1] = __builtin_amdgcn_mfma_f32_16x16x32_bf16(a, bx[1].v,
                                                           acc[mt][1], 0, 0, 0);
    }
  }

  {
    union {
      uint4 q;
      bf16x8 v;
    } bs0, bs1;
    bs0.q = stab[t * 2];
    bs1.q = stab[t * 2 + 1];
#pragma unroll
    for (int mt = 0; mt < 4; ++mt) {
      bf16x8 a = *(const bf16x8*)(s_A + (mt * 16 + l15) * AR + 64 + quad * 8);
      acc[mt][0] = __builtin_amdgcn_mfma_f32_16x16x32_bf16(a, bs0.v,
                                                           acc[mt][0], 0, 0, 0);
      acc[mt][1] = __builtin_amdgcn_mfma_f32_16x16x32_bf16(a, bs1.v,
                                                           acc[mt][1], 0, 0, 0);
    }
  }

#pragma unroll
  for (int mt = 0; mt < 4; ++mt) {
    f32x4 pv = *(const f32x4*)(s_pb + mt * 16 + quad * 4);
#pragma unroll
    for (int nt = 0; nt < 2; ++nt) {
      const int wcol = n0w + nt * 16 + l15;
#pragma unroll
      for (int r = 0; r < 4; ++r) {
        const int o = mt * 16 + quad * 4 + r;
        float v = acc[mt][nt][r];
        out[((size_t)(b * 64 + o) * 128 + h) * 128 + wcol] =
            gelu_fast(v) + pv[r];
      }
    }
  }
#undef AR
}

// ---------------------------------------------------------------------------
extern "C" void kernel_launch(void* const* d_in, const int* in_sizes, int n_in,
                              void* d_out, int out_size, void* d_ws,
                              size_t ws_size, hipStream_t stream) {
  (void)in_sizes;
  (void)n_in;
  (void)out_size;
  (void)ws_size;
  const float* x = (const float*)d_in[0];
  const float* t_emb = (const float*)d_in[1];
  const float* wr = (const float*)d_in[2];
  const float* wi = (const float*)d_in[3];
  const float* bw = (const float*)d_in[4];
  const float* bb = (const float*)d_in[5];
  const float* tw = (const float*)d_in[6];
  const float* tb = (const float*)d_in[7];
  float* out = (float*)d_out;

  char* ws = (char*)d_ws;
  // proj@0 (4K) | ftab1@64K (8K) | ftab2@96K (16K) | stab@128K (8K)
  // ofr_bf@1M (512K) | ofi_bf@2M (512K) | xfr_t@3M | xfi_t@4M | Ybf@5M..13M
  float* proj = (float*)(ws);
  uint4* ftab1 = (uint4*)(ws + (64 << 10));
  uint4* ftab2 = (uint4*)(ws + (96 << 10));
  uint4* stab = (uint4*)(ws + (128 << 10));
  unsigned* ofr_bf = (unsigned*)(ws + ((size_t)1 << 20));
  unsigned* ofi_bf = (unsigned*)(ws + ((size_t)2 << 20));
  float* xfr_t = (float*)(ws + ((size_t)3 << 20));
  float* xfi_t = (float*)(ws + ((size_t)4 << 20));
  uint4* Ybf = (uint4*)(ws + ((size_t)5 << 20));

  setup_kernel<<<17, 256, 0, stream>>>(t_emb, tw, tb, proj, ftab1, ftab2, stab);
  fwd_dft_kernel<<<1024, 256, 0, stream>>>(x, ftab1, ftab2, xfr_t, xfi_t);
  modemix_kernel<<<128, 256, 0, stream>>>(xfr_t, xfi_t, wr, wi, ofr_bf, ofi_bf);
  invh_kernel<<<512, 256, 0, stream>>>(ofr_bf, ofi_bf, Ybf);
  final_kernel<<<dim3(128, 16), 256, 0, stream>>>(x, bw, bb, proj, Ybf, stab,
                                                  out);
}